// Round 2
// baseline (69.804 us; speedup 1.0000x reference)
//
#include <hip/hip_runtime.h>

#define LEVELS 16
#define PPB    64          // points per block
#define LPT    4           // levels per thread
#define OUTW   65          // 1 + LEVELS*4
#define BLOCK  256

__global__ __launch_bounds__(BLOCK) void grid_enc_kernel(
    const float*  __restrict__ x,
    const float4* __restrict__ data,     // [T][4] 16B entries
    float*        __restrict__ out,      // [N][65]
    int N)
{
    __shared__ float s_out[PPB * OUTW];  // 4160 floats = 16640 B

    const int tid = threadIdx.x;
    const int p   = tid & (PPB - 1);     // local point 0..63
    const int g   = tid >> 6;            // level group 0..3 -> levels 4g..4g+3
    const int blockStart = blockIdx.x * PPB;
    const int n = blockStart + p;

    const bool valid = (n < N);
    float xv = 0.0f;
    if (valid) {
        xv = x[n];
        xv = fminf(fmaxf(xv, 0.0f), 1.0f);
        if (g == 0) s_out[p * OUTW] = xv;

        // Compute per-level index/frac; scales/offsets are closed-form:
        //   scale_l = 16 * 2^l (exact fp32), off_l = 16*(2^l - 1) + 8*l
        float frac[LPT];
        const float4* src0[LPT];
        #pragma unroll
        for (int k = 0; k < LPT; ++k) {
            const int l = (g << 2) + k;
            const float scale = (float)(16 << l);
            const int   off   = (16 << l) - 16 + 8 * l;
            const float fx = xv * scale;
            const float fi = floorf(fx);
            frac[k] = fx - fi;
            src0[k] = data + off + (int)fi;
        }

        // Issue all 8 gathers before any use -> 8-deep MLP per thread.
        float4 v0[LPT], v1[LPT];
        #pragma unroll
        for (int k = 0; k < LPT; ++k) {
            v0[k] = src0[k][0];
            v1[k] = src0[k][1];
        }

        #pragma unroll
        for (int k = 0; k < LPT; ++k) {
            const float w1 = frac[k];
            const float w0 = 1.0f - w1;
            float4 r;
            r.x = w0 * v0[k].x + w1 * v1[k].x;
            r.y = w0 * v0[k].y + w1 * v1[k].y;
            r.z = w0 * v0[k].z + w1 * v1[k].z;
            r.w = w0 * v0[k].w + w1 * v1[k].w;
            const int base = p * OUTW + 1 + (((g << 2) + k) << 2);
            s_out[base + 0] = r.x;
            s_out[base + 1] = r.y;
            s_out[base + 2] = r.z;
            s_out[base + 3] = r.w;
        }
    }
    __syncthreads();

    const int rem = N - blockStart;
    if (rem >= PPB) {
        // Full block: 4160 floats = 1040 float4, 16B-aligned region.
        float4* __restrict__ dst = (float4*)(out + (size_t)blockStart * OUTW);
        const float4* __restrict__ s4 = (const float4*)s_out;
        #pragma unroll
        for (int i = tid; i < PPB * OUTW / 4; i += BLOCK) dst[i] = s4[i];
    } else if (rem > 0) {
        float* dst = out + (size_t)blockStart * OUTW;
        for (int i = tid; i < rem * OUTW; i += BLOCK) dst[i] = s_out[i];
    }
}

extern "C" void kernel_launch(void* const* d_in, const int* in_sizes, int n_in,
                              void* d_out, int out_size, void* d_ws, size_t ws_size,
                              hipStream_t stream) {
    const float*  x    = (const float*)d_in[0];
    const float4* data = (const float4*)d_in[1];
    float*        out  = (float*)d_out;

    const int N = in_sizes[0];           // x is [N,1]
    const int nblocks = (N + PPB - 1) / PPB;
    grid_enc_kernel<<<nblocks, BLOCK, 0, stream>>>(x, data, out, N);
}